// Round 17
// baseline (96.135 us; speedup 1.0000x reference)
//
#include <hip/hip_runtime.h>
#include <stdint.h>

typedef unsigned short u16;
typedef unsigned int u32;

typedef __bf16 bfx8 __attribute__((ext_vector_type(8)));
typedef float fx4 __attribute__((ext_vector_type(4)));
typedef float fx16 __attribute__((ext_vector_type(16)));
typedef u16 u16x4 __attribute__((ext_vector_type(4)));
typedef u16 u16x8 __attribute__((ext_vector_type(8)));

#define GAS __attribute__((address_space(1)))
#define LAS __attribute__((address_space(3)))

__device__ __forceinline__ void gload16(const void* g, void* l) {
  __builtin_amdgcn_global_load_lds((GAS void*)g, (LAS void*)l, 16, 0, 0);
}

__device__ __forceinline__ u16 f2bf(float f) {
  union { float f; u32 u; } v; v.f = f;
  u32 r = v.u + 0x7fffu + ((v.u >> 16) & 1u);
  return (u16)(r >> 16);
}
__device__ __forceinline__ float bf2f(u16 u) {
  union { u32 u; float f; } v; v.u = ((u32)u) << 16;
  return v.f;
}

// prefix count of segments before qb (seg=256): F(qb) = sum_{j<qb} ceil((j+1)/2)
__device__ __forceinline__ int segF(int qb) { return (qb * qb + 2 * qb + (qb & 1)) >> 2; }

// ---------------- fused f32 -> bf16 convert (weights + x in one launch) ----------------
__global__ __launch_bounds__(256) void k_cvt2(const float* __restrict__ sa, u16* __restrict__ da, int na,
                                              const float* __restrict__ sb, u16* __restrict__ db, int nb) {
  int i = (blockIdx.x * 256 + threadIdx.x) * 8;
  const float* s;
  u16* d;
  if (i < na) { s = sa + i; d = da + i; }
  else {
    int j = i - na;
    if (j >= nb) return;
    s = sb + j; d = db + j;
  }
  const float4* sp = (const float4*)s;
  float4 a = sp[0], b = sp[1];
  u16x8 o;
  o[0] = f2bf(a.x); o[1] = f2bf(a.y); o[2] = f2bf(a.z); o[3] = f2bf(a.w);
  o[4] = f2bf(b.x); o[5] = f2bf(b.y); o[6] = f2bf(b.z); o[7] = f2bf(b.w);
  *(u16x8*)d = o;
}

// ---------------- output GEMM C[M,N] = A[M,K]*B[N,K]^T, f32 out ----------------
// double-buffered, stage-early (R15-proven).
__global__ __launch_bounds__(256) void k_gemm_out(const u16* __restrict__ A, const u16* __restrict__ B,
                                                  float* __restrict__ C, int M, int N, int K) {
  __shared__ char sm[32768];  // 2 x (A 8K | B 8K)
  const int tid = threadIdx.x;
  const int l = tid & 63, w = tid >> 6;
  const int li = l & 15, lg = l >> 4;
  const int bid = (blockIdx.x & 7) * 64 + (blockIdx.x >> 3);  // 512 = 8*64 bijective
  const int nbm = M >> 6;
  const int bm = bid % nbm, bn = bid / nbm;

  const u16* gsrc[4];
#pragma unroll
  for (int i = 0; i < 4; ++i) {
    int b = i * 4096 + tid * 16;
    int row, ch;
    const u16* mat;
    if (b < 8192) { row = b >> 7; mat = A + (size_t)(bm * 64 + row) * K; }
    else          { int bb = b - 8192; row = bb >> 7; mat = B + (size_t)(bn * 64 + row) * K; }
    ch = ((b >> 4) & 7) ^ (row & 7);
    gsrc[i] = mat + ch * 8;
  }

  fx4 acc[4];
#pragma unroll
  for (int jj = 0; jj < 4; ++jj)
#pragma unroll
    for (int r = 0; r < 4; ++r) acc[jj][r] = 0.f;

#pragma unroll
  for (int i = 0; i < 4; ++i) gload16(gsrc[i], sm + i * 4096 + w * 1024);
  __syncthreads();
  int cur = 0;

  for (int k0 = 0; k0 < K; k0 += 64) {
    if (k0 + 64 < K) {
      char* dst = sm + (cur ^ 1) * 16384;
#pragma unroll
      for (int i = 0; i < 4; ++i) gload16(gsrc[i] + k0 + 64, dst + i * 4096 + w * 1024);
    }
    const char* base = sm + cur * 16384;
#pragma unroll
    for (int kk = 0; kk < 2; ++kk) {
      int rowa = w * 16 + li;
      bfx8 af = *(const bfx8*)(base + rowa * 128 + (((kk * 4 + lg)) ^ (rowa & 7)) * 16);
#pragma unroll
      for (int nf = 0; nf < 4; ++nf) {
        int rowb = nf * 16 + li;
        bfx8 bfr = *(const bfx8*)(base + 8192 + rowb * 128 + ((kk * 4 + lg) ^ (rowb & 7)) * 16);
        acc[nf] = __builtin_amdgcn_mfma_f32_16x16x32_bf16(af, bfr, acc[nf], 0, 0, 0);
      }
    }
    __syncthreads();
    cur ^= 1;
  }
#pragma unroll
  for (int nf = 0; nf < 4; ++nf)
#pragma unroll
    for (int r = 0; r < 4; ++r) {
      int row = bm * 64 + w * 16 + lg * 4 + r;
      int col = bn * 64 + nf * 16 + li;
      C[(size_t)row * N + col] = acc[nf][r];
    }
}

// ---------------- fused QKV GEMM (128-thread blocks: wave owns 32 rows x 128 cols) ----------------
// mf=2 halves LDS B-read redundancy per MFMA (10 reads / 16 MFMAs vs 9/8).
// Epilogue per-lane math identical to the verified version; outer mf loop added.
__global__ __launch_bounds__(128) void k_gemm_qkv(const u16* __restrict__ A, const u16* __restrict__ B,
                                                  u16* __restrict__ qb2, u16* __restrict__ kt2,
                                                  u16* __restrict__ vt2,
                                                  const float* __restrict__ ve, const float* __restrict__ lam,
                                                  const float* __restrict__ cosp, const float* __restrict__ sinp) {
  __shared__ char sm[49152];  // 2 x (A 8K | B 16K)
  const int tid = threadIdx.x;          // 0..127
  const int l = tid & 63, w = tid >> 6; // w in {0,1}
  const int li = l & 15, lg = l >> 4;
  const int bid = (blockIdx.x & 7) * 96 + (blockIdx.x >> 3);  // 768 = 8*96 bijective
  const int bm = bid & 31, bn = bid >> 5;  // M=2048 (32), N=3072 (24)
  const int K = 1024;

  const u16* gsrc[12];
#pragma unroll
  for (int i = 0; i < 12; ++i) {
    int b = i * 2048 + w * 1024 + l * 16;  // [0, 24576)
    int row, ch;
    const u16* mat;
    if (b < 8192) { row = b >> 7; mat = A + (size_t)(bm * 64 + row) * K; }
    else          { int bb = b - 8192; row = bb >> 7; mat = B + (size_t)(bn * 128 + row) * K; }
    ch = ((b >> 4) & 7) ^ (row & 7);
    gsrc[i] = mat + ch * 8;
  }

  fx4 acc[2][8];
#pragma unroll
  for (int mf = 0; mf < 2; ++mf)
#pragma unroll
    for (int jj = 0; jj < 8; ++jj)
#pragma unroll
      for (int r = 0; r < 4; ++r) acc[mf][jj][r] = 0.f;

#pragma unroll
  for (int i = 0; i < 12; ++i) gload16(gsrc[i], sm + i * 2048 + w * 1024);
  __syncthreads();
  int cur = 0;

  for (int k0 = 0; k0 < K; k0 += 64) {
    if (k0 + 64 < K) {
      char* dst = sm + (cur ^ 1) * 24576;
#pragma unroll
      for (int i = 0; i < 12; ++i) gload16(gsrc[i] + k0 + 64, dst + i * 2048 + w * 1024);
    }
    const char* base = sm + cur * 24576;
#pragma unroll
    for (int kk = 0; kk < 2; ++kk) {
      bfx8 af[2];
#pragma unroll
      for (int mf = 0; mf < 2; ++mf) {
        int rowa = w * 32 + mf * 16 + li;
        af[mf] = *(const bfx8*)(base + rowa * 128 + ((kk * 4 + lg) ^ (rowa & 7)) * 16);
      }
#pragma unroll
      for (int nf = 0; nf < 8; ++nf) {
        int rowb = nf * 16 + li;
        bfx8 bfr = *(const bfx8*)(base + 8192 + rowb * 128 + ((kk * 4 + lg) ^ (rowb & 7)) * 16);
        acc[0][nf] = __builtin_amdgcn_mfma_f32_16x16x32_bf16(af[0], bfr, acc[0][nf], 0, 0, 0);
        acc[1][nf] = __builtin_amdgcn_mfma_f32_16x16x32_bf16(af[1], bfr, acc[1][nf], 0, 0, 0);
      }
    }
    __syncthreads();
    cur ^= 1;
  }

  const int s = bn >> 3, h = bn & 7;
  if (s < 2) {
#pragma unroll
    for (int mf = 0; mf < 2; ++mf)
#pragma unroll
      for (int r = 0; r < 4; ++r) {
        int t = bm * 64 + w * 32 + mf * 16 + lg * 4 + r;
        float ss = 0.f;
#pragma unroll
        for (int nf = 0; nf < 8; ++nf) ss += acc[mf][nf][r] * acc[mf][nf][r];
        ss += __shfl_xor(ss, 1); ss += __shfl_xor(ss, 2);
        ss += __shfl_xor(ss, 4); ss += __shfl_xor(ss, 8);
        float rn = rsqrtf(ss * (1.f / 128.f) + 1e-6f);
#pragma unroll
        for (int nf = 0; nf < 4; ++nf) {
          int dp = nf * 16 + li;
          float c = cosp[(size_t)t * 64 + dp];
          float sn = sinp[(size_t)t * 64 + dp];
          float x1 = acc[mf][nf][r] * rn, x2 = acc[mf][nf + 4][r] * rn;
          u16 o1 = f2bf(x1 * c + x2 * sn);
          u16 o2 = f2bf(-x1 * sn + x2 * c);
          if (s == 0) {
            u16* qp = qb2 + (size_t)t * 1024 + h * 128;
            qp[dp] = o1;
            qp[dp + 64] = o2;
          } else {
            u16* kp = kt2 + (size_t)h * 262144 + (size_t)(t >> 5) * 4096 + (t & 31) * 128;
            int dq = dp + 64;
            kp[(((dp >> 3) ^ (t & 7)) << 3) | (dp & 7)] = o1;
            kp[(((dq >> 3) ^ (t & 7)) << 3) | (dq & 7)] = o2;
          }
        }
      }
  } else {
    const float l0 = lam[0], l1 = lam[1];
#pragma unroll
    for (int mf = 0; mf < 2; ++mf) {
      int tb = bm * 64 + w * 32 + mf * 16 + lg * 4;
      u16* vbase = vt2 + (size_t)h * 262144 + (size_t)(tb >> 5) * 4096 + ((tb & 31) >> 3) * 1024 + (tb & 7);
#pragma unroll
      for (int nf = 0; nf < 8; ++nf) {
        int d = nf * 16 + li;
        u16x4 o;
#pragma unroll
        for (int r = 0; r < 4; ++r)
          o[r] = f2bf(l0 * acc[mf][nf][r] + l1 * ve[(size_t)(tb + r) * 1024 + h * 128 + d]);
        *(u16x4*)(vbase + d * 8) = o;
      }
    }
  }
}

// ---------------- split-K causal flash attention, fixed-base softmax ----------------
// 3-buffer distance-2 prefetch with counted-vmcnt fused barrier (R15-proven) + setprio
// around MFMA clusters (T5: attn waves have phase diversity).
__global__ __launch_bounds__(256) void k_attn2(const u16* __restrict__ qb2, const u16* __restrict__ kt2,
                                               const u16* __restrict__ vt2,
                                               u16* __restrict__ part, float* __restrict__ ml) {
  __shared__ char sm[49152];  // 3 x (K 8K + V 8K); epilogue: 4 x 8K per-wave
  const int bid = (blockIdx.x & 7) * 72 + (blockIdx.x >> 3);
  const int h = bid / 72;
  const int r72 = bid % 72;
  int qb = 15;
  while (segF(qb) > r72) --qb;
  const int s = r72 - segF(qb);
  const int q0 = qb * 128;
  const int seg0 = s * 256;
  const int seg_len = min(256, (qb + 1) * 128 - seg0);
  const int nkt = seg_len >> 5;

  const int tid = threadIdx.x;
  const int l = tid & 63, w = tid >> 6;
  const int li = l & 31, hi = l >> 5;
  const int qrow = q0 + w * 32 + li;
  const int wqmax = q0 + w * 32 + 31;
  const int wqmin = q0 + w * 32;

  bfx8 Q[8];
  {
    const u16* qp = qb2 + (size_t)qrow * 1024 + h * 128 + hi * 8;
#pragma unroll
    for (int c = 0; c < 8; ++c) Q[c] = *(const bfx8*)(qp + c * 16);
  }

  const u16* ktile = kt2 + (size_t)h * 262144 + (size_t)(seg0 >> 5) * 4096;
  const u16* vtile = vt2 + (size_t)h * 262144 + (size_t)(seg0 >> 5) * 4096;

  auto STAGE = [&](int kt, int buf) {
    char* dst = sm + buf * 16384;
    const u16* ks = ktile + (size_t)kt * 4096;
    const u16* vs = vtile + (size_t)kt * 4096;
#pragma unroll
    for (int i = 0; i < 2; ++i) {
      int j = w * 2 + i;
      gload16(ks + j * 512 + l * 8, dst + j * 1024);
      gload16(vs + j * 512 + l * 8, dst + 8192 + j * 1024);
    }
  };

  fx16 Y[4];
#pragma unroll
  for (int d = 0; d < 4; ++d)
#pragma unroll
    for (int r = 0; r < 16; ++r) Y[d][r] = 0.f;
  float l_run = 0.f;

  STAGE(0, 0);
  STAGE(1, 1);

  for (int kt = 0; kt < nkt; ++kt) {
    asm volatile("s_waitcnt vmcnt(4)\n\ts_barrier" ::: "memory");
    if (kt + 2 < nkt) STAGE(kt + 2, (kt + 2) % 3);
    const int k0 = seg0 + kt * 32;
    if (k0 <= wqmax) {
      const char* kb = sm + (kt % 3) * 16384;
      const char* vb = kb + 8192;
      fx16 S;
#pragma unroll
      for (int r = 0; r < 16; ++r) S[r] = 0.f;
      __builtin_amdgcn_s_setprio(1);
#pragma unroll
      for (int c = 0; c < 8; ++c) {
        int ch = (c * 2 + hi) ^ (li & 7);
        bfx8 kf = *(const bfx8*)(kb + li * 256 + ch * 16);
        S = __builtin_amdgcn_mfma_f32_32x32x16_bf16(kf, Q[c], S, 0, 0, 0);
      }
      __builtin_amdgcn_s_setprio(0);
      const bool nomask = (k0 + 31 <= wqmin);
      float p[16];
      float ssum = 0.f;
      if (nomask) {
#pragma unroll
        for (int r = 0; r < 16; ++r) {
          float e = __expf(fmaf(S[r], 0.12f, -16.f));
          p[r] = e; ssum += e;
        }
      } else {
#pragma unroll
        for (int r = 0; r < 16; ++r) {
          int kk = (r & 3) + 8 * (r >> 2) + 4 * hi;
          float e = (k0 + kk <= qrow) ? __expf(fmaf(S[r], 0.12f, -16.f)) : 0.f;
          p[r] = e; ssum += e;
        }
      }
      ssum += __shfl_xor(ssum, 32);
      l_run += ssum;
      u32 pk[8], pks[8];
#pragma unroll
      for (int i = 0; i < 8; ++i) pk[i] = (u32)f2bf(p[2 * i]) | ((u32)f2bf(p[2 * i + 1]) << 16);
#pragma unroll
      for (int i = 0; i < 8; ++i) pks[i] = (u32)__shfl_xor((int)pk[i], 32);
      union { u32 u[4]; bfx8 v; } P0, P1;
      if (hi == 0) {
        P0.u[0] = pk[0];  P0.u[1] = pk[1];  P0.u[2] = pks[0]; P0.u[3] = pks[1];
        P1.u[0] = pk[4];  P1.u[1] = pk[5];  P1.u[2] = pks[4]; P1.u[3] = pks[5];
      } else {
        P0.u[0] = pks[2]; P0.u[1] = pks[3]; P0.u[2] = pk[2];  P0.u[3] = pk[3];
        P1.u[0] = pks[6]; P1.u[1] = pks[7]; P1.u[2] = pk[6];  P1.u[3] = pk[7];
      }
      __builtin_amdgcn_s_setprio(1);
#pragma unroll
      for (int db = 0; db < 4; ++db) {
        int dd = db * 32 + li;
        bfx8 v0 = *(const bfx8*)(vb + hi * 2048 + dd * 16);
        bfx8 v1 = *(const bfx8*)(vb + (2 + hi) * 2048 + dd * 16);
        Y[db] = __builtin_amdgcn_mfma_f32_32x32x16_bf16(v0, P0.v, Y[db], 0, 0, 0);
        Y[db] = __builtin_amdgcn_mfma_f32_32x32x16_bf16(v1, P1.v, Y[db], 0, 0, 0);
      }
      __builtin_amdgcn_s_setprio(0);
    }
  }
  __syncthreads();  // all waves done reading sm before epilogue reuses it

  // epilogue: l store + per-wave private 8KB LDS transpose of Y partial (bf16)
  if (hi == 0) ml[(size_t)bid * 128 + w * 32 + li] = l_run;
  float* Yl = (float*)(sm + w * 8192);  // [32][64] f32, col ^ ((row&7)<<2)
  u16* pdst = part + (size_t)bid * 16384;
#pragma unroll
  for (int P = 0; P < 2; ++P) {
    asm volatile("" ::: "memory");
#pragma unroll
    for (int dh = 0; dh < 2; ++dh) {
      int db = P * 2 + dh;
#pragma unroll
      for (int r = 0; r < 16; ++r) {
        int dloc = dh * 32 + (r & 3) + 8 * (r >> 2) + 4 * hi;
        Yl[li * 64 + (dloc ^ ((li & 7) << 2))] = Y[db][r];
      }
    }
    asm volatile("" ::: "memory");
    int rr = l >> 1, c0 = (l & 1) * 32, sx = (rr & 7) << 2;
#pragma unroll
    for (int j = 0; j < 8; ++j) {
      float4 v = *(const float4*)(Yl + rr * 64 + ((c0 + j * 4) ^ sx));
      u16x4 o;
      o[0] = f2bf(v.x); o[1] = f2bf(v.y); o[2] = f2bf(v.z); o[3] = f2bf(v.w);
      *(u16x4*)(pdst + (w * 32 + rr) * 128 + P * 64 + c0 + j * 4) = o;
    }
  }
}

// ---------------- combine partials (plain sum, shared base) + gate ----------------
__global__ __launch_bounds__(256) void k_comb(const u16* __restrict__ part, const float* __restrict__ ml,
                                              const float* __restrict__ x, const float* __restrict__ gw,
                                              u16* __restrict__ y) {
  const int b = blockIdx.x;
  const int h = b >> 4, qb = b & 15;
  const int nseg = (qb + 2) >> 1;
  const int slot0 = h * 72 + segF(qb);
  const int t = threadIdx.x;
  const int r = t >> 1, hf = (t & 1) * 64;
  const int q = qb * 128 + r;

  float L = 0.f;
#pragma unroll
  for (int s = 0; s < 8; ++s)
    if (s < nseg) L += ml[(size_t)(slot0 + s) * 128 + r];

  float accv[64];
#pragma unroll
  for (int j = 0; j < 64; ++j) accv[j] = 0.f;
#pragma unroll
  for (int s = 0; s < 8; ++s) {
    if (s < nseg) {
      const u16x8* P = (const u16x8*)(part + (size_t)(slot0 + s) * 16384 + r * 128 + hf);
#pragma unroll
      for (int j = 0; j < 8; ++j) {
        u16x8 v = P[j];
#pragma unroll
        for (int e = 0; e < 8; ++e) accv[j * 8 + e] += bf2f(v[e]);
      }
    }
  }
  float dot = 0.f;
#pragma unroll
  for (int i = 0; i < 12; ++i) dot += x[(size_t)q * 1024 + i] * gw[h * 12 + i];
  float gt_ = 1.f / (1.f + __expf(-dot));
  float sc = gt_ / L;
  u16* yp = y + (size_t)q * 1024 + h * 128 + hf;
#pragma unroll
  for (int j = 0; j < 8; ++j) {
    u16x8 o;
#pragma unroll
    for (int e = 0; e < 8; ++e) o[e] = f2bf(accv[j * 8 + e] * sc);
    *(u16x8*)(yp + j * 8) = o;
  }
}

extern "C" void kernel_launch(void* const* d_in, const int* in_sizes, int n_in,
                              void* d_out, int out_size, void* d_ws, size_t ws_size,
                              hipStream_t stream) {
  const float* x = (const float*)d_in[0];
  const float* qkvo_w = (const float*)d_in[1];
  const float* gate_w = (const float*)d_in[2];
  const float* ve = (const float*)d_in[3];
  const float* lam = (const float*)d_in[4];
  const float* cosp = (const float*)d_in[5];
  const float* sinp = (const float*)d_in[6];
  float* out = (float*)d_out;

  u16* wb  = (u16*)d_ws;                  // 4M u16 (weights bf16, 8MB)
  u16* xb  = wb + 4u * 1024 * 1024;       // 2M (4MB)
  u16* qb2 = xb + 2u * 1024 * 1024;       // 2M (4MB)  q dense [2048][1024]
  u16* kt2 = qb2 + 2u * 1024 * 1024;      // 2M (4MB)  k tile-images [8][64][4096 u16]
  u16* vt2 = kt2 + 2u * 1024 * 1024;      // 2M (4MB)  v tile-images [8][64][4096 u16]
  u16* y   = vt2 + 2u * 1024 * 1024;      // 2M (4MB)
  u16* part = y + 2u * 1024 * 1024;       // 576 slots x 32KB bf16 = 18.9MB
  float* ml = (float*)(part + (size_t)576 * 16384);  // 576 x 128 f32 (0.3MB)

  k_cvt2<<<dim3(3072), dim3(256), 0, stream>>>(qkvo_w, wb, 4 * 1024 * 1024, x, xb, 2 * 1024 * 1024);
  k_gemm_qkv<<<dim3(32 * 24), dim3(128), 0, stream>>>(xb, wb, qb2, kt2, vt2, ve, lam, cosp, sinp);
  k_attn2<<<dim3(576), dim3(256), 0, stream>>>(qb2, kt2, vt2, part, ml);
  k_comb<<<dim3(128), dim3(256), 0, stream>>>(part, ml, x, gate_w, y);
  k_gemm_out<<<dim3(32 * 16), dim3(256), 0, stream>>>(y, wb + 3u * 1024 * 1024, out, 2048, 1024, 1024);
}

// Round 18
// 88.246 us; speedup vs baseline: 1.0894x; 1.0894x over previous
//
#include <hip/hip_runtime.h>
#include <stdint.h>

typedef unsigned short u16;
typedef unsigned int u32;

typedef __bf16 bfx8 __attribute__((ext_vector_type(8)));
typedef float fx4 __attribute__((ext_vector_type(4)));
typedef float fx16 __attribute__((ext_vector_type(16)));
typedef u16 u16x4 __attribute__((ext_vector_type(4)));
typedef u16 u16x8 __attribute__((ext_vector_type(8)));

#define GAS __attribute__((address_space(1)))
#define LAS __attribute__((address_space(3)))

__device__ __forceinline__ void gload16(const void* g, void* l) {
  __builtin_amdgcn_global_load_lds((GAS void*)g, (LAS void*)l, 16, 0, 0);
}

__device__ __forceinline__ u16 f2bf(float f) {
  union { float f; u32 u; } v; v.f = f;
  u32 r = v.u + 0x7fffu + ((v.u >> 16) & 1u);
  return (u16)(r >> 16);
}
__device__ __forceinline__ float bf2f(u16 u) {
  union { u32 u; float f; } v; v.u = ((u32)u) << 16;
  return v.f;
}

// prefix count of segments before qb (seg=256): F(qb) = sum_{j<qb} ceil((j+1)/2)
__device__ __forceinline__ int segF(int qb) { return (qb * qb + 2 * qb + (qb & 1)) >> 2; }

// ---------------- fused f32 -> bf16 convert (weights + x in one launch) ----------------
__global__ __launch_bounds__(256) void k_cvt2(const float* __restrict__ sa, u16* __restrict__ da, int na,
                                              const float* __restrict__ sb, u16* __restrict__ db, int nb) {
  int i = (blockIdx.x * 256 + threadIdx.x) * 8;
  const float* s;
  u16* d;
  if (i < na) { s = sa + i; d = da + i; }
  else {
    int j = i - na;
    if (j >= nb) return;
    s = sb + j; d = db + j;
  }
  const float4* sp = (const float4*)s;
  float4 a = sp[0], b = sp[1];
  u16x8 o;
  o[0] = f2bf(a.x); o[1] = f2bf(a.y); o[2] = f2bf(a.z); o[3] = f2bf(a.w);
  o[4] = f2bf(b.x); o[5] = f2bf(b.y); o[6] = f2bf(b.z); o[7] = f2bf(b.w);
  *(u16x8*)d = o;
}

// ---------------- output GEMM C[M,N] = A[M,K]*B[N,K]^T, f32 out ----------------
// double-buffered, stage-early (R15-proven).
__global__ __launch_bounds__(256) void k_gemm_out(const u16* __restrict__ A, const u16* __restrict__ B,
                                                  float* __restrict__ C, int M, int N, int K) {
  __shared__ char sm[32768];  // 2 x (A 8K | B 8K)
  const int tid = threadIdx.x;
  const int l = tid & 63, w = tid >> 6;
  const int li = l & 15, lg = l >> 4;
  const int bid = (blockIdx.x & 7) * 64 + (blockIdx.x >> 3);  // 512 = 8*64 bijective
  const int nbm = M >> 6;
  const int bm = bid % nbm, bn = bid / nbm;

  const u16* gsrc[4];
#pragma unroll
  for (int i = 0; i < 4; ++i) {
    int b = i * 4096 + tid * 16;
    int row, ch;
    const u16* mat;
    if (b < 8192) { row = b >> 7; mat = A + (size_t)(bm * 64 + row) * K; }
    else          { int bb = b - 8192; row = bb >> 7; mat = B + (size_t)(bn * 64 + row) * K; }
    ch = ((b >> 4) & 7) ^ (row & 7);
    gsrc[i] = mat + ch * 8;
  }

  fx4 acc[4];
#pragma unroll
  for (int jj = 0; jj < 4; ++jj)
#pragma unroll
    for (int r = 0; r < 4; ++r) acc[jj][r] = 0.f;

#pragma unroll
  for (int i = 0; i < 4; ++i) gload16(gsrc[i], sm + i * 4096 + w * 1024);
  __syncthreads();
  int cur = 0;

  for (int k0 = 0; k0 < K; k0 += 64) {
    if (k0 + 64 < K) {
      char* dst = sm + (cur ^ 1) * 16384;
#pragma unroll
      for (int i = 0; i < 4; ++i) gload16(gsrc[i] + k0 + 64, dst + i * 4096 + w * 1024);
    }
    const char* base = sm + cur * 16384;
#pragma unroll
    for (int kk = 0; kk < 2; ++kk) {
      int rowa = w * 16 + li;
      bfx8 af = *(const bfx8*)(base + rowa * 128 + (((kk * 4 + lg)) ^ (rowa & 7)) * 16);
#pragma unroll
      for (int nf = 0; nf < 4; ++nf) {
        int rowb = nf * 16 + li;
        bfx8 bfr = *(const bfx8*)(base + 8192 + rowb * 128 + ((kk * 4 + lg) ^ (rowb & 7)) * 16);
        acc[nf] = __builtin_amdgcn_mfma_f32_16x16x32_bf16(af, bfr, acc[nf], 0, 0, 0);
      }
    }
    __syncthreads();
    cur ^= 1;
  }
#pragma unroll
  for (int nf = 0; nf < 4; ++nf)
#pragma unroll
    for (int r = 0; r < 4; ++r) {
      int row = bm * 64 + w * 16 + lg * 4 + r;
      int col = bn * 64 + nf * 16 + li;
      C[(size_t)row * N + col] = acc[nf][r];
    }
}

// ---------------- fused QKV GEMM (R15-proven 256-thread version) ----------------
__global__ __launch_bounds__(256) void k_gemm_qkv(const u16* __restrict__ A, const u16* __restrict__ B,
                                                  u16* __restrict__ qb2, u16* __restrict__ kt2,
                                                  u16* __restrict__ vt2,
                                                  const float* __restrict__ ve, const float* __restrict__ lam,
                                                  const float* __restrict__ cosp, const float* __restrict__ sinp) {
  __shared__ char sm[49152];  // 2 x (A 8K | B 16K)
  const int tid = threadIdx.x;
  const int l = tid & 63, w = tid >> 6;
  const int li = l & 15, lg = l >> 4;
  const int bid = (blockIdx.x & 7) * 96 + (blockIdx.x >> 3);  // 768 = 8*96 bijective
  const int bm = bid & 31, bn = bid >> 5;  // M=2048 (32), N=3072 (24)
  const int K = 1024;

  const u16* gsrc[6];
#pragma unroll
  for (int i = 0; i < 6; ++i) {
    int b = i * 4096 + tid * 16;
    int row, ch;
    const u16* mat;
    if (b < 8192) { row = b >> 7; mat = A + (size_t)(bm * 64 + row) * K; }
    else          { int bb = b - 8192; row = bb >> 7; mat = B + (size_t)(bn * 128 + row) * K; }
    ch = ((b >> 4) & 7) ^ (row & 7);
    gsrc[i] = mat + ch * 8;
  }

  fx4 acc[8];
#pragma unroll
  for (int jj = 0; jj < 8; ++jj)
#pragma unroll
    for (int r = 0; r < 4; ++r) acc[jj][r] = 0.f;

#pragma unroll
  for (int i = 0; i < 6; ++i) gload16(gsrc[i], sm + i * 4096 + w * 1024);
  __syncthreads();
  int cur = 0;

  for (int k0 = 0; k0 < K; k0 += 64) {
    if (k0 + 64 < K) {
      char* dst = sm + (cur ^ 1) * 24576;
#pragma unroll
      for (int i = 0; i < 6; ++i) gload16(gsrc[i] + k0 + 64, dst + i * 4096 + w * 1024);
    }
    const char* base = sm + cur * 24576;
#pragma unroll
    for (int kk = 0; kk < 2; ++kk) {
      int rowa = w * 16 + li;
      bfx8 af = *(const bfx8*)(base + rowa * 128 + ((kk * 4 + lg) ^ (rowa & 7)) * 16);
#pragma unroll
      for (int nf = 0; nf < 8; ++nf) {
        int rowb = nf * 16 + li;
        bfx8 bfr = *(const bfx8*)(base + 8192 + rowb * 128 + ((kk * 4 + lg) ^ (rowb & 7)) * 16);
        acc[nf] = __builtin_amdgcn_mfma_f32_16x16x32_bf16(af, bfr, acc[nf], 0, 0, 0);
      }
    }
    __syncthreads();
    cur ^= 1;
  }

  const int s = bn >> 3, h = bn & 7;
  if (s < 2) {
#pragma unroll
    for (int r = 0; r < 4; ++r) {
      int t = bm * 64 + w * 16 + lg * 4 + r;
      float ss = 0.f;
#pragma unroll
      for (int nf = 0; nf < 8; ++nf) ss += acc[nf][r] * acc[nf][r];
      ss += __shfl_xor(ss, 1); ss += __shfl_xor(ss, 2);
      ss += __shfl_xor(ss, 4); ss += __shfl_xor(ss, 8);
      float rn = rsqrtf(ss * (1.f / 128.f) + 1e-6f);
#pragma unroll
      for (int nf = 0; nf < 4; ++nf) {
        int dp = nf * 16 + li;
        float c = cosp[(size_t)t * 64 + dp];
        float sn = sinp[(size_t)t * 64 + dp];
        float x1 = acc[nf][r] * rn, x2 = acc[nf + 4][r] * rn;
        u16 o1 = f2bf(x1 * c + x2 * sn);
        u16 o2 = f2bf(-x1 * sn + x2 * c);
        if (s == 0) {
          u16* qp = qb2 + (size_t)t * 1024 + h * 128;
          qp[dp] = o1;
          qp[dp + 64] = o2;
        } else {
          u16* kp = kt2 + (size_t)h * 262144 + (size_t)(t >> 5) * 4096 + (t & 31) * 128;
          int dq = dp + 64;
          kp[(((dp >> 3) ^ (t & 7)) << 3) | (dp & 7)] = o1;
          kp[(((dq >> 3) ^ (t & 7)) << 3) | (dq & 7)] = o2;
        }
      }
    }
  } else {
    const float l0 = lam[0], l1 = lam[1];
    int tb = bm * 64 + w * 16 + lg * 4;
    u16* vbase = vt2 + (size_t)h * 262144 + (size_t)(tb >> 5) * 4096 + ((tb & 31) >> 3) * 1024 + (tb & 7);
#pragma unroll
    for (int nf = 0; nf < 8; ++nf) {
      int d = nf * 16 + li;
      u16x4 o;
#pragma unroll
      for (int r = 0; r < 4; ++r)
        o[r] = f2bf(l0 * acc[nf][r] + l1 * ve[(size_t)(tb + r) * 1024 + h * 128 + d]);
      *(u16x4*)(vbase + d * 8) = o;
    }
  }
}

// ---------------- split-K causal flash attention, fixed-base softmax ----------------
// 3-buffer distance-2 prefetch with counted-vmcnt fused barrier (R15-proven).
__global__ __launch_bounds__(256) void k_attn2(const u16* __restrict__ qb2, const u16* __restrict__ kt2,
                                               const u16* __restrict__ vt2,
                                               u16* __restrict__ part, float* __restrict__ ml) {
  __shared__ char sm[49152];  // 3 x (K 8K + V 8K); epilogue: 4 x 8K per-wave
  const int bid = (blockIdx.x & 7) * 72 + (blockIdx.x >> 3);
  const int h = bid / 72;
  const int r72 = bid % 72;
  int qb = 15;
  while (segF(qb) > r72) --qb;
  const int s = r72 - segF(qb);
  const int q0 = qb * 128;
  const int seg0 = s * 256;
  const int seg_len = min(256, (qb + 1) * 128 - seg0);
  const int nkt = seg_len >> 5;

  const int tid = threadIdx.x;
  const int l = tid & 63, w = tid >> 6;
  const int li = l & 31, hi = l >> 5;
  const int qrow = q0 + w * 32 + li;
  const int wqmax = q0 + w * 32 + 31;
  const int wqmin = q0 + w * 32;

  bfx8 Q[8];
  {
    const u16* qp = qb2 + (size_t)qrow * 1024 + h * 128 + hi * 8;
#pragma unroll
    for (int c = 0; c < 8; ++c) Q[c] = *(const bfx8*)(qp + c * 16);
  }

  const u16* ktile = kt2 + (size_t)h * 262144 + (size_t)(seg0 >> 5) * 4096;
  const u16* vtile = vt2 + (size_t)h * 262144 + (size_t)(seg0 >> 5) * 4096;

  auto STAGE = [&](int kt, int buf) {
    char* dst = sm + buf * 16384;
    const u16* ks = ktile + (size_t)kt * 4096;
    const u16* vs = vtile + (size_t)kt * 4096;
#pragma unroll
    for (int i = 0; i < 2; ++i) {
      int j = w * 2 + i;
      gload16(ks + j * 512 + l * 8, dst + j * 1024);
      gload16(vs + j * 512 + l * 8, dst + 8192 + j * 1024);
    }
  };

  fx16 Y[4];
#pragma unroll
  for (int d = 0; d < 4; ++d)
#pragma unroll
    for (int r = 0; r < 16; ++r) Y[d][r] = 0.f;
  float l_run = 0.f;

  STAGE(0, 0);
  STAGE(1, 1);

  for (int kt = 0; kt < nkt; ++kt) {
    asm volatile("s_waitcnt vmcnt(4)\n\ts_barrier" ::: "memory");
    if (kt + 2 < nkt) STAGE(kt + 2, (kt + 2) % 3);
    const int k0 = seg0 + kt * 32;
    if (k0 <= wqmax) {
      const char* kb = sm + (kt % 3) * 16384;
      const char* vb = kb + 8192;
      fx16 S;
#pragma unroll
      for (int r = 0; r < 16; ++r) S[r] = 0.f;
#pragma unroll
      for (int c = 0; c < 8; ++c) {
        int ch = (c * 2 + hi) ^ (li & 7);
        bfx8 kf = *(const bfx8*)(kb + li * 256 + ch * 16);
        S = __builtin_amdgcn_mfma_f32_32x32x16_bf16(kf, Q[c], S, 0, 0, 0);
      }
      const bool nomask = (k0 + 31 <= wqmin);
      float p[16];
      float ssum = 0.f;
      if (nomask) {
#pragma unroll
        for (int r = 0; r < 16; ++r) {
          float e = __expf(fmaf(S[r], 0.12f, -16.f));
          p[r] = e; ssum += e;
        }
      } else {
#pragma unroll
        for (int r = 0; r < 16; ++r) {
          int kk = (r & 3) + 8 * (r >> 2) + 4 * hi;
          float e = (k0 + kk <= qrow) ? __expf(fmaf(S[r], 0.12f, -16.f)) : 0.f;
          p[r] = e; ssum += e;
        }
      }
      ssum += __shfl_xor(ssum, 32);
      l_run += ssum;
      u32 pk[8], pks[8];
#pragma unroll
      for (int i = 0; i < 8; ++i) pk[i] = (u32)f2bf(p[2 * i]) | ((u32)f2bf(p[2 * i + 1]) << 16);
#pragma unroll
      for (int i = 0; i < 8; ++i) pks[i] = (u32)__shfl_xor((int)pk[i], 32);
      union { u32 u[4]; bfx8 v; } P0, P1;
      if (hi == 0) {
        P0.u[0] = pk[0];  P0.u[1] = pk[1];  P0.u[2] = pks[0]; P0.u[3] = pks[1];
        P1.u[0] = pk[4];  P1.u[1] = pk[5];  P1.u[2] = pks[4]; P1.u[3] = pks[5];
      } else {
        P0.u[0] = pks[2]; P0.u[1] = pks[3]; P0.u[2] = pk[2];  P0.u[3] = pk[3];
        P1.u[0] = pks[6]; P1.u[1] = pks[7]; P1.u[2] = pk[6];  P1.u[3] = pk[7];
      }
#pragma unroll
      for (int db = 0; db < 4; ++db) {
        int dd = db * 32 + li;
        bfx8 v0 = *(const bfx8*)(vb + hi * 2048 + dd * 16);
        bfx8 v1 = *(const bfx8*)(vb + (2 + hi) * 2048 + dd * 16);
        Y[db] = __builtin_amdgcn_mfma_f32_32x32x16_bf16(v0, P0.v, Y[db], 0, 0, 0);
        Y[db] = __builtin_amdgcn_mfma_f32_32x32x16_bf16(v1, P1.v, Y[db], 0, 0, 0);
      }
    }
  }
  __syncthreads();  // all waves done reading sm before epilogue reuses it

  // epilogue: l store + per-wave private 8KB LDS transpose of Y partial (bf16)
  if (hi == 0) ml[(size_t)bid * 128 + w * 32 + li] = l_run;
  float* Yl = (float*)(sm + w * 8192);  // [32][64] f32, col ^ ((row&7)<<2)
  u16* pdst = part + (size_t)bid * 16384;
#pragma unroll
  for (int P = 0; P < 2; ++P) {
    asm volatile("" ::: "memory");
#pragma unroll
    for (int dh = 0; dh < 2; ++dh) {
      int db = P * 2 + dh;
#pragma unroll
      for (int r = 0; r < 16; ++r) {
        int dloc = dh * 32 + (r & 3) + 8 * (r >> 2) + 4 * hi;
        Yl[li * 64 + (dloc ^ ((li & 7) << 2))] = Y[db][r];
      }
    }
    asm volatile("" ::: "memory");
    int rr = l >> 1, c0 = (l & 1) * 32, sx = (rr & 7) << 2;
#pragma unroll
    for (int j = 0; j < 8; ++j) {
      float4 v = *(const float4*)(Yl + rr * 64 + ((c0 + j * 4) ^ sx));
      u16x4 o;
      o[0] = f2bf(v.x); o[1] = f2bf(v.y); o[2] = f2bf(v.z); o[3] = f2bf(v.w);
      *(u16x4*)(pdst + (w * 32 + rr) * 128 + P * 64 + c0 + j * 4) = o;
    }
  }
}

// ---------------- combine partials (plain sum, shared base) + gate ----------------
// 256 blocks x 128 threads: one block per (h, qb, 64-row half) -> 1 block/CU.
__global__ __launch_bounds__(128) void k_comb(const u16* __restrict__ part, const float* __restrict__ ml,
                                              const float* __restrict__ x, const float* __restrict__ gw,
                                              u16* __restrict__ y) {
  const int b = blockIdx.x;
  const int h = b >> 5;
  const int rem = b & 31;
  const int qb = rem >> 1, half = rem & 1;
  const int nseg = (qb + 2) >> 1;
  const int slot0 = h * 72 + segF(qb);
  const int t = threadIdx.x;
  const int r = half * 64 + (t >> 1), hf = (t & 1) * 64;
  const int q = qb * 128 + r;

  float L = 0.f;
#pragma unroll
  for (int s = 0; s < 8; ++s)
    if (s < nseg) L += ml[(size_t)(slot0 + s) * 128 + r];

  float accv[64];
#pragma unroll
  for (int j = 0; j < 64; ++j) accv[j] = 0.f;
#pragma unroll
  for (int s = 0; s < 8; ++s) {
    if (s < nseg) {
      const u16x8* P = (const u16x8*)(part + (size_t)(slot0 + s) * 16384 + r * 128 + hf);
#pragma unroll
      for (int j = 0; j < 8; ++j) {
        u16x8 v = P[j];
#pragma unroll
        for (int e = 0; e < 8; ++e) accv[j * 8 + e] += bf2f(v[e]);
      }
    }
  }
  float dot = 0.f;
#pragma unroll
  for (int i = 0; i < 12; ++i) dot += x[(size_t)q * 1024 + i] * gw[h * 12 + i];
  float gt_ = 1.f / (1.f + __expf(-dot));
  float sc = gt_ / L;
  u16* yp = y + (size_t)q * 1024 + h * 128 + hf;
#pragma unroll
  for (int j = 0; j < 8; ++j) {
    u16x8 o;
#pragma unroll
    for (int e = 0; e < 8; ++e) o[e] = f2bf(accv[j * 8 + e] * sc);
    *(u16x8*)(yp + j * 8) = o;
  }
}

extern "C" void kernel_launch(void* const* d_in, const int* in_sizes, int n_in,
                              void* d_out, int out_size, void* d_ws, size_t ws_size,
                              hipStream_t stream) {
  const float* x = (const float*)d_in[0];
  const float* qkvo_w = (const float*)d_in[1];
  const float* gate_w = (const float*)d_in[2];
  const float* ve = (const float*)d_in[3];
  const float* lam = (const float*)d_in[4];
  const float* cosp = (const float*)d_in[5];
  const float* sinp = (const float*)d_in[6];
  float* out = (float*)d_out;

  u16* wb  = (u16*)d_ws;                  // 4M u16 (weights bf16, 8MB)
  u16* xb  = wb + 4u * 1024 * 1024;       // 2M (4MB)
  u16* qb2 = xb + 2u * 1024 * 1024;       // 2M (4MB)  q dense [2048][1024]
  u16* kt2 = qb2 + 2u * 1024 * 1024;      // 2M (4MB)  k tile-images [8][64][4096 u16]
  u16* vt2 = kt2 + 2u * 1024 * 1024;      // 2M (4MB)  v tile-images [8][64][4096 u16]
  u16* y   = vt2 + 2u * 1024 * 1024;      // 2M (4MB)
  u16* part = y + 2u * 1024 * 1024;       // 576 slots x 32KB bf16 = 18.9MB
  float* ml = (float*)(part + (size_t)576 * 16384);  // 576 x 128 f32 (0.3MB)

  k_cvt2<<<dim3(3072), dim3(256), 0, stream>>>(qkvo_w, wb, 4 * 1024 * 1024, x, xb, 2 * 1024 * 1024);
  k_gemm_qkv<<<dim3(32 * 24), dim3(256), 0, stream>>>(xb, wb, qb2, kt2, vt2, ve, lam, cosp, sinp);
  k_attn2<<<dim3(576), dim3(256), 0, stream>>>(qb2, kt2, vt2, part, ml);
  k_comb<<<dim3(256), dim3(128), 0, stream>>>(part, ml, x, gate_w, y);
  k_gemm_out<<<dim3(32 * 16), dim3(256), 0, stream>>>(y, wb + 3u * 1024 * 1024, out, 2048, 1024, 1024);
}